// Round 7
// baseline (3330.603 us; speedup 1.0000x reference)
//
#include <hip/hip_runtime.h>
#include <math.h>

// ---------------- problem constants ----------------
#define Lsz   1024
#define Tsz   32
#define Bsz   64
#define DIN   300
#define REG   36
#define Rsz   128
#define R3sz  384
#define H3sz  3072
#define GENROWS 49152   // R3sz * Rsz
#define NC    2048      // caption columns c = t*64 + b
#define KPAD  304       // DIN padded to /16

__device__ __forceinline__ float sigf(float x) { return 1.f / (1.f + __expf(-x)); }

// =====================================================================
// Generic tiled SGEMM (64x64 tile, 4x4 reg tile), row-major C only.
// z-dim selects a second problem (W2/bias2/C2) sharing the same A.
// =====================================================================
__global__ __launch_bounds__(256) void gemm_bias(
    const float* __restrict__ A, int lda,
    const float* __restrict__ W1, const float* __restrict__ W2, int ldw, int woff,
    const float* __restrict__ bias1, const float* __restrict__ bias2,
    float* __restrict__ C1, float* __restrict__ C2,
    int M, int N, int K)
{
    const float* W = blockIdx.z ? W2 : W1;
    const float* bias = blockIdx.z ? bias2 : bias1;
    float* C = blockIdx.z ? C2 : C1;
    __shared__ float As[16][68];
    __shared__ float Ws[16][68];
    int tid = threadIdx.x;
    int tx = tid & 15, ty = tid >> 4;
    int m0 = blockIdx.y * 64, n0 = blockIdx.x * 64;
    float acc[4][4];
#pragma unroll
    for (int i = 0; i < 4; i++)
#pragma unroll
        for (int j = 0; j < 4; j++) acc[i][j] = 0.f;

    for (int k0 = 0; k0 < K; k0 += 16) {
#pragma unroll
        for (int l = 0; l < 4; l++) {
            int e = l * 256 + tid;
            int kk = e & 15, mm = e >> 4;
            int m = m0 + mm, k = k0 + kk;
            As[kk][mm] = (m < M && k < K) ? A[(size_t)m * lda + k] : 0.f;
        }
#pragma unroll
        for (int l = 0; l < 4; l++) {
            int e = l * 256 + tid;
            int kk = e & 15, nn = e >> 4;
            int n = n0 + nn, k = k0 + kk;
            Ws[kk][nn] = (n < N && k < K) ? W[(size_t)n * ldw + woff + k] : 0.f;
        }
        __syncthreads();
#pragma unroll
        for (int kk = 0; kk < 16; kk++) {
            float4 a4 = *(const float4*)&As[kk][ty * 4];
            float4 w4 = *(const float4*)&Ws[kk][tx * 4];
            float av[4] = {a4.x, a4.y, a4.z, a4.w};
            float wv[4] = {w4.x, w4.y, w4.z, w4.w};
#pragma unroll
            for (int i = 0; i < 4; i++)
#pragma unroll
                for (int j = 0; j < 4; j++) acc[i][j] = fmaf(av[i], wv[j], acc[i][j]);
        }
        __syncthreads();
    }
#pragma unroll
    for (int i = 0; i < 4; i++) {
        int m = m0 + ty * 4 + i;
        if (m >= M) continue;
#pragma unroll
        for (int j = 0; j < 4; j++) {
            int n = n0 + tx * 4 + j;
            if (n >= N) continue;
            C[(size_t)m * N + n] = acc[i][j] + (bias ? bias[n] : 0.f);
        }
    }
}

// =====================================================================
// cap_embed [b][t][d] -> capTr [k][t*64+b], k padded to 304 with zeros.
// grid (32 t, 5 kc), 256 thr. Coalesced both directions via LDS.
// =====================================================================
__global__ __launch_bounds__(256) void captr_kernel(
    const float* __restrict__ cap_embed, float* __restrict__ capTr)
{
    __shared__ float s[64][65];
    int t = blockIdx.x, kc = blockIdx.y;
    int tid = threadIdx.x;
#pragma unroll
    for (int l = 0; l < 16; l++) {
        int e = l * 256 + tid;
        int b = e >> 6, kk = e & 63;
        int k = kc * 64 + kk;
        s[b][kk] = (k < DIN) ? cap_embed[((size_t)b * Tsz + t) * DIN + k] : 0.f;
    }
    __syncthreads();
#pragma unroll
    for (int l = 0; l < 16; l++) {
        int e = l * 256 + tid;
        int kk = e >> 6, b = e & 63;
        int k = kc * 64 + kk;
        if (k < KPAD)
            capTr[(size_t)k * NC + t * 64 + b] = s[b][kk];
    }
}

// =====================================================================
// out[n][c] = sum_k W[n][k]*capTr[k][c] + bias[n].  Fully coalesced.
// Tile 128(n) x 64(c), 8x4 reg tile. z selects (W1,b1,C1)/(W2,b2,C2).
// Used for gi (rows=3072) and cap_reduced (rows=128).
// =====================================================================
__global__ __launch_bounds__(256) void gemm_nt(
    const float* __restrict__ capTr,
    const float* __restrict__ W1, const float* __restrict__ W2,
    const float* __restrict__ bias1, const float* __restrict__ bias2,
    float* __restrict__ C1, float* __restrict__ C2)
{
    const float* W = blockIdx.z ? W2 : W1;
    const float* bias = blockIdx.z ? bias2 : bias1;
    float* C = blockIdx.z ? C2 : C1;
    __shared__ float Ws[16][132];
    __shared__ float Xs[16][68];
    int tid = threadIdx.x, tx = tid & 15, ty = tid >> 4;
    int m0 = blockIdx.y * 128, c0 = blockIdx.x * 64;
    float acc[8][4];
#pragma unroll
    for (int i = 0; i < 8; i++)
#pragma unroll
        for (int j = 0; j < 4; j++) acc[i][j] = 0.f;

    for (int k0 = 0; k0 < KPAD; k0 += 16) {
#pragma unroll
        for (int l = 0; l < 8; l++) {
            int e = l * 256 + tid;
            int kk = e & 15, mm = e >> 4;
            int k = k0 + kk;
            Ws[kk][mm] = (k < DIN) ? W[(size_t)(m0 + mm) * DIN + k] : 0.f;
        }
#pragma unroll
        for (int l = 0; l < 4; l++) {
            int e = l * 256 + tid;
            int kk = e & 15, cc = e >> 4;
            Xs[kk][cc] = capTr[(size_t)(k0 + kk) * NC + c0 + cc];
        }
        __syncthreads();
#pragma unroll
        for (int kk = 0; kk < 16; kk++) {
            float a[8], x[4];
            *(float4*)&a[0] = *(const float4*)&Ws[kk][ty * 8];
            *(float4*)&a[4] = *(const float4*)&Ws[kk][ty * 8 + 4];
            *(float4*)&x[0] = *(const float4*)&Xs[kk][tx * 4];
#pragma unroll
            for (int i = 0; i < 8; i++)
#pragma unroll
                for (int j = 0; j < 4; j++) acc[i][j] = fmaf(a[i], x[j], acc[i][j]);
        }
        __syncthreads();
    }
#pragma unroll
    for (int i = 0; i < 8; i++) {
        int n = m0 + ty * 8 + i;
        float bv = bias[n];
        *(float4*)&C[(size_t)n * NC + c0 + tx * 4] =
            make_float4(acc[i][0] + bv, acc[i][1] + bv, acc[i][2] + bv, acc[i][3] + bv);
    }
}

// =====================================================================
// Generated weights: out[i][rk] = dot(genW[rk][:], base[i][:]) + bias[rk].
// =====================================================================
__global__ __launch_bounds__(256) void genw_kernel(
    const float* __restrict__ gen_Wih, const float* __restrict__ gen_bih,
    const float* __restrict__ gen_Whh, const float* __restrict__ gen_bhh,
    const float* __restrict__ gen_Wbih, const float* __restrict__ gen_bbih,
    const float* __restrict__ gen_Wbhh, const float* __restrict__ gen_bbhh,
    const float* __restrict__ base,
    float* __restrict__ WihAll, float* __restrict__ WhhAll,
    float* __restrict__ bihAll, float* __restrict__ bhhAll)
{
    int z = blockIdx.y;
    const float* W; const float* bi; float* out; int nr; int rk;
    if (blockIdx.x < 192) {
        rk = blockIdx.x * 256 + threadIdx.x;
        W = z ? gen_Whh : gen_Wih;  bi = z ? gen_bhh : gen_bih;
        out = z ? WhhAll : WihAll;  nr = GENROWS;
    } else {
        rk = (blockIdx.x - 192) * 256 + threadIdx.x;
        if (rk >= R3sz) return;
        W = z ? gen_Wbhh : gen_Wbih; bi = z ? gen_bbhh : gen_bbih;
        out = z ? bhhAll : bihAll;   nr = R3sz;
    }
    const float* wrow = W + (size_t)rk * Rsz;
    float acc[64];
#pragma unroll
    for (int i = 0; i < 64; i++) acc[i] = 0.f;
    for (int pc = 0; pc < Rsz; pc += 16) {
        float w[16];
        *(float4*)&w[0]  = *(const float4*)&wrow[pc];
        *(float4*)&w[4]  = *(const float4*)&wrow[pc + 4];
        *(float4*)&w[8]  = *(const float4*)&wrow[pc + 8];
        *(float4*)&w[12] = *(const float4*)&wrow[pc + 12];
#pragma unroll
        for (int i = 0; i < 64; i++) {
            const float4* bp = (const float4*)(base + (size_t)i * Rsz + pc);
            float4 b0 = bp[0], b1 = bp[1], b2 = bp[2], b3 = bp[3];
            float s = acc[i];
            s = fmaf(w[0], b0.x, s);  s = fmaf(w[1], b0.y, s);
            s = fmaf(w[2], b0.z, s);  s = fmaf(w[3], b0.w, s);
            s = fmaf(w[4], b1.x, s);  s = fmaf(w[5], b1.y, s);
            s = fmaf(w[6], b1.z, s);  s = fmaf(w[7], b1.w, s);
            s = fmaf(w[8], b2.x, s);  s = fmaf(w[9], b2.y, s);
            s = fmaf(w[10], b2.z, s); s = fmaf(w[11], b2.w, s);
            s = fmaf(w[12], b3.x, s); s = fmaf(w[13], b3.y, s);
            s = fmaf(w[14], b3.z, s); s = fmaf(w[15], b3.w, s);
            acc[i] = s;
        }
    }
    float bv = bi[rk];
#pragma unroll
    for (int i = 0; i < 64; i++)
        out[(size_t)i * nr + rk] = acc[i] + bv;
}

// =====================================================================
// Fused image-side precompute. grid 64.
// =====================================================================
__global__ __launch_bounds__(256) void img_kernel(
    const float* __restrict__ img_embed, const float* __restrict__ W_reduce_img,
    const float* __restrict__ b_reduce_img,
    float* __restrict__ base, float* __restrict__ iv)
{
    int i = blockIdx.x;
    int tid = threadIdx.x;
    __shared__ float row[Lsz];
    __shared__ float ps[4];
    for (int c = tid; c < Lsz; c += 256) {
        float s = 0.f;
        for (int r = 0; r < REG; r++) s += img_embed[((size_t)i * REG + r) * Lsz + c];
        row[c] = s * (1.f / (float)REG);
    }
    __syncthreads();
    float ss = 0.f;
    for (int c = tid; c < Lsz; c += 256) { float x = row[c]; ss = fmaf(x, x, ss); }
#pragma unroll
    for (int off = 32; off; off >>= 1) ss += __shfl_down(ss, off, 64);
    int lane = tid & 63, w = tid >> 6;
    if (lane == 0) ps[w] = ss;
    __syncthreads();
    float inv = 1.f / (sqrtf(ps[0] + ps[1] + ps[2] + ps[3]) + 1e-8f);
    for (int c = tid; c < Lsz; c += 256)
        iv[(size_t)i * Lsz + c] = row[c] * inv;
    for (int o = w * 32; o < w * 32 + 32; o++) {
        float a = 0.f;
        const float* wr = W_reduce_img + (size_t)o * Lsz + lane * 16;
        const float* rr = row + lane * 16;
#pragma unroll
        for (int u = 0; u < 16; u++) a = fmaf(wr[u], rr[u], a);
#pragma unroll
        for (int off = 32; off; off >>= 1) a += __shfl_down(a, off, 64);
        if (lane == 0) base[(size_t)i * Rsz + o] = a + b_reduce_img[o];
    }
}

// =====================================================================
// Fused per-step recurrence: grid 384 x 512 threads, ONE launch/step.
// Phase A (all blocks): partial GEMM slice -> global partials ->
// release-signal per-group counter. Owner blocks (ks==0) acquire-spin
// for their group's producers, then do the gate math (phase B).
// Deadlock-free: producers never wait; consumers wait only on producers.
//  bid<128  : caption. dir=bid>>6; jg=(bid&63)>>2; ks=bid&3 (K-slice 256).
//  bid>=128 : gen, XCD-swizzled i; jg in {0,1}; ks 0=ih,1=hh.
// =====================================================================
__global__ __launch_bounds__(512) void step_fused(
    const float* __restrict__ giT2_f, const float* __restrict__ giT2_b,
    float* __restrict__ hfT, float* __restrict__ hbT,
    const float* __restrict__ Whh_f, const float* __restrict__ Whh_b,
    const float* __restrict__ bhh_f, const float* __restrict__ bhh_b,
    const float* __restrict__ capT2,
    const float* __restrict__ WihAll, const float* __restrict__ WhhAll,
    const float* __restrict__ bihAll, const float* __restrict__ bhhAll,
    const float* __restrict__ hprevT, float* __restrict__ hcurT,
    float* __restrict__ hmaxT,
    float* __restrict__ pcap, float* __restrict__ pgen,
    int* __restrict__ flags, int step)
{
    __shared__ float As[16][196];
    __shared__ float Hs[16][68];
    int tid = threadIdx.x;
    int tx = tid & 15, ty = tid >> 4;   // ty in [0,32)
    int bid = blockIdx.x;

    const float* Wp; const float* Xb; float* P;
    size_t xstride; int ldw, Hjump, jg, nchunk, grp, target;
    bool owner, skipA;

    if (bid < 128) {
        int dir = bid >> 6; int rem = bid & 63;
        jg = rem >> 2; int ks = rem & 3;
        grp = dir * 16 + jg; target = 4; owner = (ks == 0);
        skipA = (step == 0);
        const float* Whh = dir ? Whh_b : Whh_f;
        const float* hT  = dir ? hbT   : hfT;
        int t  = dir ? (Tsz - 1 - step) : step;
        int tp = dir ? (t + 1) : (t - 1);
        Wp = Whh + ks * 256;
        Xb = hT + ((size_t)tp * Lsz + ks * 256) * Bsz;
        xstride = Bsz;
        P  = pcap + ((((size_t)dir * 4 + ks) * 16 + jg) * 192) * 64;
        ldw = Lsz; Hjump = Lsz; nchunk = 16;
    } else {
        int g = bid - 128;
        int x = g & 7, rest = g >> 3;
        int i = x + 8 * (rest >> 2);
        int sub = rest & 3; jg = sub >> 1; int ks = sub & 1;
        grp = 32 + i * 2 + jg; target = 2; owner = (ks == 0);
        skipA = (ks == 1 && step == 0);
        Wp = (ks ? WhhAll : WihAll) + (size_t)i * GENROWS;
        if (ks) { Xb = hprevT + (size_t)i * Rsz * Bsz; xstride = Bsz; }
        else    { Xb = capT2 + (size_t)step * 64;      xstride = NC; }
        P  = pgen + ((((size_t)i * 2 + ks) * 2 + jg) * 192) * 64;
        ldw = Rsz; Hjump = Rsz; nchunk = 8;
    }

    if (!skipA) {
        size_t rowoff[6];
#pragma unroll
        for (int l = 0; l < 6; l++) {
            int mm = ty + 32 * l;
            int gg = mm >> 6, jl = mm & 63;
            rowoff[l] = (size_t)(gg * Hjump + jg * 64 + jl) * ldw;
        }
        float acc[6][4];
#pragma unroll
        for (int i = 0; i < 6; i++)
#pragma unroll
            for (int j = 0; j < 4; j++) acc[i][j] = 0.f;

        for (int c = 0; c < nchunk; c++) {
            int k0 = c * 16;
#pragma unroll
            for (int l = 0; l < 6; l++)
                As[tx][ty + 32 * l] = Wp[rowoff[l] + k0 + tx];
#pragma unroll
            for (int l = 0; l < 2; l++) {
                int e = l * 512 + tid;
                int kk = e >> 6, b = e & 63;
                Hs[kk][b] = Xb[(size_t)(k0 + kk) * xstride + b];
            }
            __syncthreads();
#pragma unroll
            for (int kk = 0; kk < 16; kk++) {
                float a[6], hb[4];
#pragma unroll
                for (int i = 0; i < 6; i++) a[i] = As[kk][ty * 6 + i];
                *(float4*)&hb[0] = *(const float4*)&Hs[kk][tx * 4];
#pragma unroll
                for (int i = 0; i < 6; i++)
#pragma unroll
                    for (int j = 0; j < 4; j++) acc[i][j] = fmaf(a[i], hb[j], acc[i][j]);
            }
            __syncthreads();
        }
#pragma unroll
        for (int i = 0; i < 6; i++) {
            int mm = ty * 6 + i;
            *(float4*)&P[(size_t)mm * 64 + tx * 4] =
                make_float4(acc[i][0], acc[i][1], acc[i][2], acc[i][3]);
        }
    }

    // ---- signal ----
    __syncthreads();
    int* fl = flags + step * 160 + grp;
    if (tid == 0) {
        __threadfence();
        __hip_atomic_fetch_add(fl, 1, __ATOMIC_RELEASE, __HIP_MEMORY_SCOPE_AGENT);
    }
    if (!owner) return;

    // ---- owner: wait for group's producers ----
    if (tid == 0) {
        while (__hip_atomic_load(fl, __ATOMIC_ACQUIRE, __HIP_MEMORY_SCOPE_AGENT) < target)
            __builtin_amdgcn_s_sleep(2);
        __threadfence();
    }
    __syncthreads();

    // ---- phase B: gates ----
    int b = tid & 63;
    if (bid < 128) {
        int dir = bid >> 6;
        const float* giT = dir ? giT2_b : giT2_f;
        float* hT        = dir ? hbT   : hfT;
        const float* bhh = dir ? bhh_b : bhh_f;
        int t  = dir ? (Tsz - 1 - step) : step;
        int tp = dir ? (t + 1) : (t - 1);
#pragma unroll
        for (int u = 0; u < 8; u++) {
            int jl = u * 8 + (tid >> 6);
            int j = jg * 64 + jl;
            float gh[3] = {0.f, 0.f, 0.f};
            if (step > 0) {
#pragma unroll
                for (int ks = 0; ks < 4; ks++) {
                    size_t pb = ((((size_t)dir * 4 + ks) * 16 + jg) * 192) * 64;
#pragma unroll
                    for (int g = 0; g < 3; g++)
                        gh[g] += pcap[pb + (size_t)(g * 64 + jl) * 64 + b];
                }
            }
            size_t gc = (size_t)t * 64 + b;
            float gr = giT[(size_t)j * NC + gc];
            float gz = giT[(size_t)(Lsz + j) * NC + gc];
            float gn = giT[(size_t)(2 * Lsz + j) * NC + gc];
            float hp = (step > 0) ? hT[((size_t)tp * Lsz + j) * Bsz + b] : 0.f;
            float r = sigf(gr + gh[0] + bhh[j]);
            float z = sigf(gz + gh[1] + bhh[Lsz + j]);
            float n = tanhf(gn + r * (gh[2] + bhh[2 * Lsz + j]));
            hT[((size_t)t * Lsz + j) * Bsz + b] = (1.f - z) * n + z * hp;
        }
    } else {
        int g2 = bid - 128;
        int x = g2 & 7, rest = g2 >> 3;
        int i = x + 8 * (rest >> 2);
        const float* bih  = bihAll + (size_t)i * R3sz;
        const float* bhh  = bhhAll + (size_t)i * R3sz;
        size_t p0 = ((((size_t)i * 2 + 0) * 2 + jg) * 192) * 64;
        size_t p1 = ((((size_t)i * 2 + 1) * 2 + jg) * 192) * 64;
#pragma unroll
        for (int u = 0; u < 8; u++) {
            int jl = u * 8 + (tid >> 6);
            int j = jg * 64 + jl;
            float sih[3], shh[3];
#pragma unroll
            for (int g = 0; g < 3; g++) {
                sih[g] = pgen[p0 + (size_t)(g * 64 + jl) * 64 + b];
                shh[g] = (step > 0) ? pgen[p1 + (size_t)(g * 64 + jl) * 64 + b] : 0.f;
            }
            float r = sigf(sih[0] + bih[j] + shh[0] + bhh[j]);
            float z = sigf(sih[1] + bih[Rsz + j] + shh[1] + bhh[Rsz + j]);
            float n = tanhf(sih[2] + bih[2 * Rsz + j] + r * (shh[2] + bhh[2 * Rsz + j]));
            float hp = (step > 0) ? hprevT[((size_t)i * Rsz + j) * Bsz + b] : 0.f;
            float h = (1.f - z) * n + z * hp;
            size_t idx = ((size_t)i * Rsz + j) * Bsz + b;
            hcurT[idx] = h;
            hmaxT[idx] = (step == 0) ? h : fmaxf(hmaxT[idx], h);
        }
    }
}

// =====================================================================
// txt = (hf+hb)/2, [t][c][b] -> [b][t][c] transpose. grid (32, 16).
// =====================================================================
__global__ __launch_bounds__(256) void txt_combine(
    const float* __restrict__ hfT, const float* __restrict__ hbT,
    float* __restrict__ txt)
{
    __shared__ float s[64][65];
    int t = blockIdx.x;
    int c0 = blockIdx.y * 64;
    int tid = threadIdx.x;
#pragma unroll
    for (int l = 0; l < 16; l++) {
        int e = l * 256 + tid;
        int cc = e >> 6, b = e & 63;
        size_t idx = ((size_t)t * Lsz + c0 + cc) * Bsz + b;
        s[cc][b] = 0.5f * (hfT[idx] + hbT[idx]);
    }
    __syncthreads();
#pragma unroll
    for (int l = 0; l < 16; l++) {
        int e = l * 256 + tid;
        int b = e >> 6, cc = e & 63;
        txt[((size_t)b * Tsz + t) * Lsz + c0 + cc] = s[cc][b];
    }
}

// =====================================================================
// Self-attention: logits -> softmax -> apply + residual. grid (64, 8).
// =====================================================================
__global__ __launch_bounds__(256) void attn_kernel(
    const float* __restrict__ q, const float* __restrict__ kmat,
    const float* __restrict__ v, const float* __restrict__ txt,
    const float* __restrict__ gamma_p, float* __restrict__ xattn)
{
    __shared__ float qs[32][129];
    __shared__ float ks[32][129];
    __shared__ float As[32][33];
    int b = blockIdx.x;
    int c0 = blockIdx.y * 128;
    int tid = threadIdx.x;
    for (int e = tid; e < Tsz * Rsz; e += 256) {
        qs[e >> 7][e & 127] = q[(size_t)b * Tsz * Rsz + e];
        ks[e >> 7][e & 127] = kmat[(size_t)b * Tsz * Rsz + e];
    }
    __syncthreads();
    for (int e = tid; e < Tsz * Tsz; e += 256) {
        int t = e >> 5, ss = e & 31;
        float acc = 0.f;
#pragma unroll 4
        for (int o = 0; o < Rsz; o++) acc = fmaf(qs[t][o], ks[ss][o], acc);
        As[t][ss] = acc;
    }
    __syncthreads();
    if (tid < 32) {
        int t = tid;
        float mx = -1e30f;
#pragma unroll
        for (int ss = 0; ss < 32; ss++) mx = fmaxf(mx, As[t][ss]);
        float sum = 0.f;
        float ex[32];
#pragma unroll
        for (int ss = 0; ss < 32; ss++) { ex[ss] = __expf(As[t][ss] - mx); sum += ex[ss]; }
        float inv = 1.f / sum;
#pragma unroll
        for (int ss = 0; ss < 32; ss++) As[t][ss] = ex[ss] * inv;
    }
    __syncthreads();
    float gamma = *gamma_p;
    for (int e = tid; e < Tsz * 128; e += 256) {
        int tt = e >> 7, c = c0 + (e & 127);
        float acc = 0.f;
#pragma unroll 8
        for (int ss = 0; ss < Tsz; ss++)
            acc = fmaf(As[tt][ss], v[((size_t)b * Tsz + ss) * Lsz + c], acc);
        size_t oidx = ((size_t)b * Tsz + tt) * Lsz + c;
        xattn[oidx] = gamma * acc + txt[oidx];
    }
}

// ---------------- length-masked mean pool, grid (64,4) ----------------
__global__ __launch_bounds__(256) void pool_kernel(
    const float* __restrict__ xattn, const int* __restrict__ lens,
    float* __restrict__ txt_embed)
{
    int b = blockIdx.x;
    int c = blockIdx.y * 256 + threadIdx.x;
    int len = lens[b];
    float s = 0.f;
    for (int t = 0; t < len; t++) s += xattn[((size_t)b * Tsz + t) * Lsz + c];
    txt_embed[(size_t)b * Lsz + c] = s / (float)len;
}

// =====================================================================
// base_fc[b][n] = dot(txt_emb[b][:], W_txt_fc[n][0:1024]). grid 256.
// =====================================================================
__global__ __launch_bounds__(256) void basefc_kernel(
    const float* __restrict__ temb, const float* __restrict__ W,
    float* __restrict__ out)
{
    int lane = threadIdx.x & 63, w = threadIdx.x >> 6;
    int n = blockIdx.x * 4 + w;
    const float* wr = W + (size_t)n * (Rsz + Lsz) + lane * 16;
    float wv[16];
#pragma unroll
    for (int u = 0; u < 4; u++) *(float4*)&wv[u * 4] = *(const float4*)&wr[u * 4];
    for (int b = 0; b < Bsz; b++) {
        const float* te = temb + (size_t)b * Lsz + lane * 16;
        float tv[16];
#pragma unroll
        for (int u = 0; u < 4; u++) *(float4*)&tv[u * 4] = *(const float4*)&te[u * 4];
        float a = 0.f;
#pragma unroll
        for (int u = 0; u < 16; u++) a = fmaf(wv[u], tv[u], a);
#pragma unroll
        for (int off = 32; off; off >>= 1) a += __shfl_down(a, off, 64);
        if (lane == 0) out[(size_t)b * Lsz + n] = a;
    }
}

// ---------------- hmax [i][j][b] -> [(i*64+b)][j], grid 64 ----------------
__global__ __launch_bounds__(256) void hmax_transpose(
    const float* __restrict__ hmaxT, float* __restrict__ hstd)
{
    __shared__ float s[128][65];
    int i = blockIdx.x, tid = threadIdx.x;
#pragma unroll
    for (int l = 0; l < 32; l++) {
        int e = l * 256 + tid;
        int j = e >> 6, b = e & 63;
        s[j][b] = hmaxT[((size_t)i * Rsz + j) * Bsz + b];
    }
    __syncthreads();
#pragma unroll
    for (int l = 0; l < 32; l++) {
        int e = l * 256 + tid;
        int b = e >> 7, j = e & 127;
        hstd[((size_t)i * Bsz + b) * Rsz + j] = s[j][b];
    }
}

// ---------------- final fused l2norm + cosine, grid 4096 ----------------
__global__ __launch_bounds__(256) void sims_kernel(
    const float* __restrict__ fc_delta, const float* __restrict__ base_fc,
    const float* __restrict__ bfc, const float* __restrict__ iv,
    float* __restrict__ out)
{
    int m = blockIdx.x;          // i*64 + b
    int i = m >> 6, b = m & 63;
    int tid = threadIdx.x;
    float s1 = 0.f, s2 = 0.f;
    for (int c = tid; c < Lsz; c += 256) {
        float f = fc_delta[(size_t)m * Lsz + c] + base_fc[(size_t)b * Lsz + c] + bfc[c];
        s1 = fmaf(f, f, s1);
        s2 = fmaf(f, iv[(size_t)i * Lsz + c], s2);
    }
#pragma unroll
    for (int off = 32; off; off >>= 1) {
        s1 += __shfl_down(s1, off, 64);
        s2 += __shfl_down(s2, off, 64);
    }
    __shared__ float p1[4], p2[4];
    int w = tid >> 6;
    if ((tid & 63) == 0) { p1[w] = s1; p2[w] = s2; }
    __syncthreads();
    if (tid == 0) {
        float t1 = p1[0] + p1[1] + p1[2] + p1[3];
        float t2 = p2[0] + p2[1] + p2[2] + p2[3];
        out[m] = t2 / (sqrtf(t1) + 1e-8f);
    }
}

// =====================================================================
extern "C" void kernel_launch(void* const* d_in, const int* in_sizes, int n_in,
                              void* d_out, int out_size, void* d_ws, size_t ws_size,
                              hipStream_t stream)
{
    const float* img_embed    = (const float*)d_in[0];
    const float* cap_embed    = (const float*)d_in[1];
    const int*   lens         = (const int*)d_in[2];
    const float* W_reduce_img = (const float*)d_in[3];
    const float* b_reduce_img = (const float*)d_in[4];
    const float* W_reduce_txt = (const float*)d_in[5];
    const float* b_reduce_txt = (const float*)d_in[6];
    const float* gru_Wih_f    = (const float*)d_in[7];
    const float* gru_Whh_f    = (const float*)d_in[8];
    const float* gru_bih_f    = (const float*)d_in[9];
    const float* gru_bhh_f    = (const float*)d_in[10];
    const float* gru_Wih_b    = (const float*)d_in[11];
    const float* gru_Whh_b    = (const float*)d_in[12];
    const float* gru_bih_b    = (const float*)d_in[13];
    const float* gru_bhh_b    = (const float*)d_in[14];
    const float* sa_Wq        = (const float*)d_in[15];
    const float* sa_bq        = (const float*)d_in[16];
    const float* sa_Wk        = (const float*)d_in[17];
    const float* sa_bk        = (const float*)d_in[18];
    const float* sa_Wv        = (const float*)d_in[19];
    const float* sa_bv        = (const float*)d_in[20];
    const float* sa_gamma     = (const float*)d_in[21];
    const float* gen_Wih      = (const float*)d_in[22];
    const float* gen_bih      = (const float*)d_in[23];
    const float* gen_Whh      = (const float*)d_in[24];
    const float* gen_bhh      = (const float*)d_in[25];
    const float* gen_Wbih     = (const float*)d_in[26];
    const float* gen_bbih     = (const float*)d_in[27];
    const float* gen_Wbhh     = (const float*)d_in[28];
    const float* gen_bbhh     = (const float*)d_in[29];
    const float* W_txt_fc     = (const float*)d_in[30];
    const float* b_txt_fc     = (const float*)d_in[31];

    float* ws = (float*)d_ws;
    size_t off = 0;
    auto alloc = [&](size_t n) { float* p = ws + off; off += n; return p; };
    float* giT2_f   = alloc((size_t)H3sz * NC);          // [3072][2048]
    float* giT2_b   = alloc((size_t)H3sz * NC);
    float* hfT      = alloc((size_t)Tsz * Lsz * Bsz);
    float* hbT      = alloc((size_t)Tsz * Lsz * Bsz);
    float* capTr    = alloc((size_t)KPAD * NC);          // [304][2048]
    float* capT2    = alloc((size_t)Rsz * NC);           // [128][2048]
    float* txt      = alloc((size_t)Bsz * Tsz * Lsz);
    float* qbuf     = alloc((size_t)Bsz * Tsz * Rsz);
    float* kbuf     = alloc((size_t)Bsz * Tsz * Rsz);
    float* vbuf     = alloc((size_t)Bsz * Tsz * Lsz);
    float* xattn    = alloc((size_t)Bsz * Tsz * Lsz);
    float* txt_emb  = alloc((size_t)Bsz * Lsz);
    float* base     = alloc((size_t)Bsz * Rsz);
    float* iv       = alloc((size_t)Bsz * Lsz);
    float* WihAll   = alloc((size_t)Bsz * GENROWS);
    float* WhhAll   = alloc((size_t)Bsz * GENROWS);
    float* bihAll   = alloc((size_t)Bsz * R3sz);
    float* bhhAll   = alloc((size_t)Bsz * R3sz);
    float* hA       = alloc((size_t)Bsz * Rsz * Bsz);
    float* hB       = alloc((size_t)Bsz * Rsz * Bsz);
    float* hmaxT    = alloc((size_t)Bsz * Rsz * Bsz);
    float* hstd     = alloc((size_t)Bsz * Bsz * Rsz);
    float* base_fc  = alloc((size_t)Bsz * Lsz);
    float* fc_delta = alloc((size_t)Bsz * Bsz * Lsz);
    int*   flags    = (int*)alloc(8192);                 // 32 steps x 160 groups
    // Recurrence partials alias later-stage scratch (disjoint lifetimes):
    float* pcap = fc_delta;   // 1.57M floats within fc_delta (4.2M)
    float* pgen = vbuf;       // 3.15M floats within vbuf+xattn (4.2M)

    // 0) zero the sync flags (graph-capture-safe)
    hipMemsetAsync(flags, 0, 32 * 160 * sizeof(int), stream);

    // 1) image-side precompute + generated weights
    img_kernel<<<64, 256, 0, stream>>>(img_embed, W_reduce_img, b_reduce_img, base, iv);
    genw_kernel<<<dim3(194, 2), 256, 0, stream>>>(gen_Wih, gen_bih, gen_Whh, gen_bhh,
        gen_Wbih, gen_bbih, gen_Wbhh, gen_bbhh, base, WihAll, WhhAll, bihAll, bhhAll);

    // 2) caption transpose, then gi (both dirs) + cap_reduced, all coalesced
    captr_kernel<<<dim3(32, 5), 256, 0, stream>>>(cap_embed, capTr);
    gemm_nt<<<dim3(32, 24, 2), 256, 0, stream>>>(capTr, gru_Wih_f, gru_Wih_b,
        gru_bih_f, gru_bih_b, giT2_f, giT2_b);
    gemm_nt<<<dim3(32, 1, 1), 256, 0, stream>>>(capTr, W_reduce_txt, W_reduce_txt,
        b_reduce_txt, b_reduce_txt, capT2, capT2);

    // 3) recurrences: ONE fused kernel per step (intra-kernel A->B sync)
    for (int s = 0; s < Tsz; s++) {
        const float* hp = (s & 1) ? hA : hB;   // unused at s==0
        float* hc = (s & 1) ? hB : hA;
        if (s == 0) hp = hA;
        step_fused<<<384, 512, 0, stream>>>(giT2_f, giT2_b, hfT, hbT,
            gru_Whh_f, gru_Whh_b, gru_bhh_f, gru_bhh_b, capT2,
            WihAll, WhhAll, bihAll, bhhAll, hp, hc, hmaxT, pcap, pgen, flags, s);
    }
    hmax_transpose<<<64, 256, 0, stream>>>(hmaxT, hstd);

    // 4) combine + self-attention
    txt_combine<<<dim3(32, 16), 256, 0, stream>>>(hfT, hbT, txt);
    gemm_bias<<<dim3(2, 32, 2), 256, 0, stream>>>(txt, Lsz, sa_Wq, sa_Wk, Lsz, 0,
        sa_bq, sa_bk, qbuf, kbuf, Bsz * Tsz, Rsz, Lsz);
    gemm_bias<<<dim3(16, 32), 256, 0, stream>>>(txt, Lsz, sa_Wv, sa_Wv, Lsz, 0,
        sa_bv, sa_bv, vbuf, vbuf, Bsz * Tsz, Lsz, Lsz);
    attn_kernel<<<dim3(64, 8), 256, 0, stream>>>(qbuf, kbuf, vbuf, txt, sa_gamma, xattn);

    // 5) pool + image-independent FC part
    pool_kernel<<<dim3(64, 4), 256, 0, stream>>>(xattn, lens, txt_emb);
    basefc_kernel<<<256, 256, 0, stream>>>(txt_emb, W_txt_fc, base_fc);

    // 6) per-(image,caption) FC delta + fused norm/cosine
    gemm_bias<<<dim3(16, 64), 256, 0, stream>>>(hstd, Rsz, W_txt_fc, W_txt_fc,
        Rsz + Lsz, Lsz, nullptr, nullptr, fc_delta, fc_delta, Bsz * Bsz, Lsz, Rsz);
    sims_kernel<<<4096, 256, 0, stream>>>(fc_delta, base_fc, b_txt_fc, iv, (float*)d_out);
}

// Round 8
// 2089.925 us; speedup vs baseline: 1.5936x; 1.5936x over previous
//
#include <hip/hip_runtime.h>
#include <math.h>

// ---------------- problem constants ----------------
#define Lsz   1024
#define Tsz   32
#define Bsz   64
#define DIN   300
#define REG   36
#define Rsz   128
#define R3sz  384
#define H3sz  3072
#define GENROWS 49152   // R3sz * Rsz
#define NC    2048      // caption columns c = t*64 + b
#define KPAD  304       // DIN padded to /16

__device__ __forceinline__ float sigf(float x) { return 1.f / (1.f + __expf(-x)); }

// =====================================================================
// Generic tiled SGEMM (64x64 tile, 4x4 reg tile), row-major C.
// z-dim selects a second problem (W2/bias2/C2) sharing the same A.
// =====================================================================
__global__ __launch_bounds__(256) void gemm_bias(
    const float* __restrict__ A, int lda,
    const float* __restrict__ W1, const float* __restrict__ W2, int ldw, int woff,
    const float* __restrict__ bias1, const float* __restrict__ bias2,
    float* __restrict__ C1, float* __restrict__ C2,
    int M, int N, int K)
{
    const float* W = blockIdx.z ? W2 : W1;
    const float* bias = blockIdx.z ? bias2 : bias1;
    float* C = blockIdx.z ? C2 : C1;
    __shared__ float As[16][68];
    __shared__ float Ws[16][68];
    int tid = threadIdx.x;
    int tx = tid & 15, ty = tid >> 4;
    int m0 = blockIdx.y * 64, n0 = blockIdx.x * 64;
    float acc[4][4];
#pragma unroll
    for (int i = 0; i < 4; i++)
#pragma unroll
        for (int j = 0; j < 4; j++) acc[i][j] = 0.f;

    for (int k0 = 0; k0 < K; k0 += 16) {
#pragma unroll
        for (int l = 0; l < 4; l++) {
            int e = l * 256 + tid;
            int kk = e & 15, mm = e >> 4;
            int m = m0 + mm, k = k0 + kk;
            As[kk][mm] = (m < M && k < K) ? A[(size_t)m * lda + k] : 0.f;
        }
#pragma unroll
        for (int l = 0; l < 4; l++) {
            int e = l * 256 + tid;
            int kk = e & 15, nn = e >> 4;
            int n = n0 + nn, k = k0 + kk;
            Ws[kk][nn] = (n < N && k < K) ? W[(size_t)n * ldw + woff + k] : 0.f;
        }
        __syncthreads();
#pragma unroll
        for (int kk = 0; kk < 16; kk++) {
            float4 a4 = *(const float4*)&As[kk][ty * 4];
            float4 w4 = *(const float4*)&Ws[kk][tx * 4];
            float av[4] = {a4.x, a4.y, a4.z, a4.w};
            float wv[4] = {w4.x, w4.y, w4.z, w4.w};
#pragma unroll
            for (int i = 0; i < 4; i++)
#pragma unroll
                for (int j = 0; j < 4; j++) acc[i][j] = fmaf(av[i], wv[j], acc[i][j]);
        }
        __syncthreads();
    }
#pragma unroll
    for (int i = 0; i < 4; i++) {
        int m = m0 + ty * 4 + i;
        if (m >= M) continue;
#pragma unroll
        for (int j = 0; j < 4; j++) {
            int n = n0 + tx * 4 + j;
            if (n >= N) continue;
            C[(size_t)m * N + n] = acc[i][j] + (bias ? bias[n] : 0.f);
        }
    }
}

// =====================================================================
// Generic transpose: in [R][Cin] -> out [Cpad][R], zero-padding cols.
// grid (ceil(Cpad/64), ceil(R/64)).
// =====================================================================
__global__ __launch_bounds__(256) void transp_kernel(
    const float* __restrict__ in, float* __restrict__ out,
    int R, int Cin, int Cpad)
{
    __shared__ float s[64][65];
    int c0 = blockIdx.x * 64, r0 = blockIdx.y * 64;
    int tid = threadIdx.x;
#pragma unroll
    for (int l = 0; l < 16; l++) {
        int e = l * 256 + tid;
        int rr = e >> 6, cc = e & 63;
        int r = r0 + rr, c = c0 + cc;
        s[rr][cc] = (r < R && c < Cin) ? in[(size_t)r * Cin + c] : 0.f;
    }
    __syncthreads();
#pragma unroll
    for (int l = 0; l < 16; l++) {
        int e = l * 256 + tid;
        int cc = e >> 6, rr = e & 63;
        int c = c0 + cc, r = r0 + rr;
        if (c < Cpad && r < R) out[(size_t)c * R + r] = s[rr][cc];
    }
}

// =====================================================================
// Gen-weight transpose: [i][384][128] -> [i][128][384], both matrices.
// grid (2, 6, 128): z = i*2 + mat.
// =====================================================================
__global__ __launch_bounds__(256) void trans_gen(
    const float* __restrict__ WihAll, const float* __restrict__ WhhAll,
    float* __restrict__ WihAllT, float* __restrict__ WhhAllT)
{
    __shared__ float s[64][65];
    int z = blockIdx.z;
    int i = z >> 1, mat = z & 1;
    const float* in = (mat ? WhhAll : WihAll) + (size_t)i * GENROWS;
    float* out      = (mat ? WhhAllT : WihAllT) + (size_t)i * GENROWS;
    int c0 = blockIdx.x * 64, r0 = blockIdx.y * 64;
    int tid = threadIdx.x;
#pragma unroll
    for (int l = 0; l < 16; l++) {
        int e = l * 256 + tid;
        int rr = e >> 6, cc = e & 63;
        s[rr][cc] = in[(size_t)(r0 + rr) * Rsz + c0 + cc];
    }
    __syncthreads();
#pragma unroll
    for (int l = 0; l < 16; l++) {
        int e = l * 256 + tid;
        int cc = e >> 6, rr = e & 63;
        out[(size_t)(c0 + cc) * R3sz + r0 + rr] = s[rr][cc];
    }
}

// =====================================================================
// cap_embed [b][t][d] -> capTr [k][t*64+b], k zero-padded to 304.
// grid (32 t, 5 kc), 256 thr.
// =====================================================================
__global__ __launch_bounds__(256) void captr_kernel(
    const float* __restrict__ cap_embed, float* __restrict__ capTr)
{
    __shared__ float s[64][65];
    int t = blockIdx.x, kc = blockIdx.y;
    int tid = threadIdx.x;
#pragma unroll
    for (int l = 0; l < 16; l++) {
        int e = l * 256 + tid;
        int b = e >> 6, kk = e & 63;
        int k = kc * 64 + kk;
        s[b][kk] = (k < DIN) ? cap_embed[((size_t)b * Tsz + t) * DIN + k] : 0.f;
    }
    __syncthreads();
#pragma unroll
    for (int l = 0; l < 16; l++) {
        int e = l * 256 + tid;
        int kk = e >> 6, b = e & 63;
        int k = kc * 64 + kk;
        if (k < KPAD)
            capTr[(size_t)k * NC + t * 64 + b] = s[b][kk];
    }
}

// =====================================================================
// All-transposed GEMM: C[n][c] = sum_k WT[k][n] * X[k][c] + bias[n].
// WT is [KPAD][Ntot], X is [KPAD][NC]. Tile 128x128, 8x8 reg tile,
// all staging via float4 (coalesced global, vector LDS).
// grid (NC/128, Ntot/128, z) — dims must divide exactly.
// =====================================================================
__global__ __launch_bounds__(256) void gemm_tt(
    const float* __restrict__ WT1, const float* __restrict__ WT2,
    const float* __restrict__ X,
    const float* __restrict__ b1, const float* __restrict__ b2,
    float* __restrict__ C1, float* __restrict__ C2, int Ntot)
{
    const float* WT = blockIdx.z ? WT2 : WT1;
    const float* bias = blockIdx.z ? b2 : b1;
    float* C = blockIdx.z ? C2 : C1;
    __shared__ float Ws[16][132];
    __shared__ float Xs[16][132];
    int tid = threadIdx.x, tx = tid & 15, ty = tid >> 4;
    int c0 = blockIdx.x * 128, n0 = blockIdx.y * 128;
    float acc[8][8];
#pragma unroll
    for (int i = 0; i < 8; i++)
#pragma unroll
        for (int j = 0; j < 8; j++) acc[i][j] = 0.f;

    for (int k0 = 0; k0 < KPAD; k0 += 16) {
#pragma unroll
        for (int l = 0; l < 2; l++) {
            int e = l * 256 + tid;
            int l16 = e & 15, seg = e >> 4;
            int kk = seg & 15, half = seg >> 4;
            int col = half * 64 + l16 * 4;
            *(float4*)&Ws[kk][col] = *(const float4*)&WT[(size_t)(k0 + kk) * Ntot + n0 + col];
            *(float4*)&Xs[kk][col] = *(const float4*)&X[(size_t)(k0 + kk) * NC + c0 + col];
        }
        __syncthreads();
#pragma unroll
        for (int kk = 0; kk < 16; kk++) {
            float a[8], x[8];
            *(float4*)&a[0] = *(const float4*)&Ws[kk][ty * 8];
            *(float4*)&a[4] = *(const float4*)&Ws[kk][ty * 8 + 4];
            *(float4*)&x[0] = *(const float4*)&Xs[kk][tx * 8];
            *(float4*)&x[4] = *(const float4*)&Xs[kk][tx * 8 + 4];
#pragma unroll
            for (int i = 0; i < 8; i++)
#pragma unroll
                for (int j = 0; j < 8; j++) acc[i][j] = fmaf(a[i], x[j], acc[i][j]);
        }
        __syncthreads();
    }
#pragma unroll
    for (int i = 0; i < 8; i++) {
        int n = n0 + ty * 8 + i;
        float bv = bias[n];
        *(float4*)&C[(size_t)n * NC + c0 + tx * 8] =
            make_float4(acc[i][0] + bv, acc[i][1] + bv, acc[i][2] + bv, acc[i][3] + bv);
        *(float4*)&C[(size_t)n * NC + c0 + tx * 8 + 4] =
            make_float4(acc[i][4] + bv, acc[i][5] + bv, acc[i][6] + bv, acc[i][7] + bv);
    }
}

// =====================================================================
// Generated weights: out[i][rk] = dot(genW[rk][:], base[i][:]) + bias[rk].
// =====================================================================
__global__ __launch_bounds__(256) void genw_kernel(
    const float* __restrict__ gen_Wih, const float* __restrict__ gen_bih,
    const float* __restrict__ gen_Whh, const float* __restrict__ gen_bhh,
    const float* __restrict__ gen_Wbih, const float* __restrict__ gen_bbih,
    const float* __restrict__ gen_Wbhh, const float* __restrict__ gen_bbhh,
    const float* __restrict__ base,
    float* __restrict__ WihAll, float* __restrict__ WhhAll,
    float* __restrict__ bihAll, float* __restrict__ bhhAll)
{
    int z = blockIdx.y;
    const float* W; const float* bi; float* out; int nr; int rk;
    if (blockIdx.x < 192) {
        rk = blockIdx.x * 256 + threadIdx.x;
        W = z ? gen_Whh : gen_Wih;  bi = z ? gen_bhh : gen_bih;
        out = z ? WhhAll : WihAll;  nr = GENROWS;
    } else {
        rk = (blockIdx.x - 192) * 256 + threadIdx.x;
        if (rk >= R3sz) return;
        W = z ? gen_Wbhh : gen_Wbih; bi = z ? gen_bbhh : gen_bbih;
        out = z ? bhhAll : bihAll;   nr = R3sz;
    }
    const float* wrow = W + (size_t)rk * Rsz;
    float acc[64];
#pragma unroll
    for (int i = 0; i < 64; i++) acc[i] = 0.f;
    for (int pc = 0; pc < Rsz; pc += 16) {
        float w[16];
        *(float4*)&w[0]  = *(const float4*)&wrow[pc];
        *(float4*)&w[4]  = *(const float4*)&wrow[pc + 4];
        *(float4*)&w[8]  = *(const float4*)&wrow[pc + 8];
        *(float4*)&w[12] = *(const float4*)&wrow[pc + 12];
#pragma unroll
        for (int i = 0; i < 64; i++) {
            const float4* bp = (const float4*)(base + (size_t)i * Rsz + pc);
            float4 b0 = bp[0], b1 = bp[1], b2 = bp[2], b3 = bp[3];
            float s = acc[i];
            s = fmaf(w[0], b0.x, s);  s = fmaf(w[1], b0.y, s);
            s = fmaf(w[2], b0.z, s);  s = fmaf(w[3], b0.w, s);
            s = fmaf(w[4], b1.x, s);  s = fmaf(w[5], b1.y, s);
            s = fmaf(w[6], b1.z, s);  s = fmaf(w[7], b1.w, s);
            s = fmaf(w[8], b2.x, s);  s = fmaf(w[9], b2.y, s);
            s = fmaf(w[10], b2.z, s); s = fmaf(w[11], b2.w, s);
            s = fmaf(w[12], b3.x, s); s = fmaf(w[13], b3.y, s);
            s = fmaf(w[14], b3.z, s); s = fmaf(w[15], b3.w, s);
            acc[i] = s;
        }
    }
    float bv = bi[rk];
#pragma unroll
    for (int i = 0; i < 64; i++)
        out[(size_t)i * nr + rk] = acc[i] + bv;
}

// =====================================================================
// Fused image-side precompute. grid 64.
// =====================================================================
__global__ __launch_bounds__(256) void img_kernel(
    const float* __restrict__ img_embed, const float* __restrict__ W_reduce_img,
    const float* __restrict__ b_reduce_img,
    float* __restrict__ base, float* __restrict__ iv)
{
    int i = blockIdx.x;
    int tid = threadIdx.x;
    __shared__ float row[Lsz];
    __shared__ float ps[4];
    for (int c = tid; c < Lsz; c += 256) {
        float s = 0.f;
        for (int r = 0; r < REG; r++) s += img_embed[((size_t)i * REG + r) * Lsz + c];
        row[c] = s * (1.f / (float)REG);
    }
    __syncthreads();
    float ss = 0.f;
    for (int c = tid; c < Lsz; c += 256) { float x = row[c]; ss = fmaf(x, x, ss); }
#pragma unroll
    for (int off = 32; off; off >>= 1) ss += __shfl_down(ss, off, 64);
    int lane = tid & 63, w = tid >> 6;
    if (lane == 0) ps[w] = ss;
    __syncthreads();
    float inv = 1.f / (sqrtf(ps[0] + ps[1] + ps[2] + ps[3]) + 1e-8f);
    for (int c = tid; c < Lsz; c += 256)
        iv[(size_t)i * Lsz + c] = row[c] * inv;
    for (int o = w * 32; o < w * 32 + 32; o++) {
        float a = 0.f;
        const float* wr = W_reduce_img + (size_t)o * Lsz + lane * 16;
        const float* rr = row + lane * 16;
#pragma unroll
        for (int u = 0; u < 16; u++) a = fmaf(wr[u], rr[u], a);
#pragma unroll
        for (int off = 32; off; off >>= 1) a += __shfl_down(a, off, 64);
        if (lane == 0) base[(size_t)i * Rsz + o] = a + b_reduce_img[o];
    }
}

// =====================================================================
// Recurrence phase A, fully vectorized via pre-transposed weights.
// grid 512 x 256 thr, 2 blocks/CU, uniform 1.57 MFMA per block.
//  bid<256  : caption. dir=bid>>7; jg=(bid>>3)&15; ks=bid&7 (K-slice 128).
//  bid>=256 : gen, XCD-swizzled i; ks 0=ih,1=hh; jg in {0,1}.
// Tile M=192 (3 gates x 64 j), N=64, K=128 in 8 chunks.
// Staging: dwordx4 global -> b128 LDS write; compute: 3x b128 broadcast
// A-reads + 1 b128 X-read per 48 FMA.
// =====================================================================
__global__ __launch_bounds__(256) void step_gemm2(
    const float* __restrict__ hfT, const float* __restrict__ hbT,
    const float* __restrict__ WhhT_f, const float* __restrict__ WhhT_b,
    const float* __restrict__ capT2,
    const float* __restrict__ WihAllT, const float* __restrict__ WhhAllT,
    const float* __restrict__ hprevT,
    float* __restrict__ pcap, float* __restrict__ pgen, int step)
{
    __shared__ float As[16][196];
    __shared__ float Hs[16][68];
    int tid = threadIdx.x;
    int tx = tid & 15, ty = tid >> 4;
    int bid = blockIdx.x;

    const float* WT; const float* X; float* P;
    int ldn, gstride, jg, kbase;
    size_t xstride;

    if (bid < 256) {
        if (step == 0) return;
        int dir = bid >> 7; int rem = bid & 127;
        jg = rem >> 3; int ks = rem & 7;
        WT = dir ? WhhT_b : WhhT_f;        // [1024][3072]
        kbase = ks * 128;
        const float* hT = dir ? hbT : hfT;
        int t  = dir ? (Tsz - 1 - step) : step;
        int tp = dir ? (t + 1) : (t - 1);
        X = hT + ((size_t)tp * Lsz + ks * 128) * Bsz;
        xstride = Bsz;
        P = pcap + ((((size_t)dir * 8 + ks) * 16 + jg) * 192) * 64;
        ldn = H3sz; gstride = Lsz;
    } else {
        int g = bid - 256;
        int x = g & 7, rest = g >> 3;
        int i = x + 8 * (rest >> 2);
        int sub = rest & 3; int ks = sub >> 1; jg = sub & 1;
        if (ks == 1 && step == 0) return;
        WT = (ks ? WhhAllT : WihAllT) + (size_t)i * GENROWS;   // [128][384]
        kbase = 0;
        if (ks) { X = hprevT + (size_t)i * Rsz * Bsz; xstride = Bsz; }
        else    { X = capT2 + (size_t)step * 64;      xstride = NC;  }
        P = pgen + ((((size_t)i * 2 + ks) * 2 + jg) * 192) * 64;
        ldn = R3sz; gstride = Rsz;
    }

    float acc[12][4];
#pragma unroll
    for (int i = 0; i < 12; i++)
#pragma unroll
        for (int j = 0; j < 4; j++) acc[i][j] = 0.f;

    int lane16 = tid & 15;
    for (int c = 0; c < 8; c++) {
        int k0 = c * 16;
#pragma unroll
        for (int l = 0; l < 3; l++) {
            int e = l * 256 + tid;
            int l16 = e & 15, seg = e >> 4;
            int kk = seg & 15, gate = seg >> 4;     // gate in 0..2
            const float* src = WT + (size_t)(kbase + k0 + kk) * ldn
                               + gate * gstride + jg * 64 + l16 * 4;
            *(float4*)&As[kk][gate * 64 + l16 * 4] = *(const float4*)src;
        }
        {
            int kk = tid >> 4;
            *(float4*)&Hs[kk][lane16 * 4] =
                *(const float4*)&X[(size_t)(k0 + kk) * xstride + lane16 * 4];
        }
        __syncthreads();
#pragma unroll
        for (int kk = 0; kk < 16; kk++) {
            float a[12], hb[4];
            *(float4*)&a[0] = *(const float4*)&As[kk][ty * 12];
            *(float4*)&a[4] = *(const float4*)&As[kk][ty * 12 + 4];
            *(float4*)&a[8] = *(const float4*)&As[kk][ty * 12 + 8];
            *(float4*)&hb[0] = *(const float4*)&Hs[kk][tx * 4];
#pragma unroll
            for (int i = 0; i < 12; i++)
#pragma unroll
                for (int j = 0; j < 4; j++) acc[i][j] = fmaf(a[i], hb[j], acc[i][j]);
        }
        __syncthreads();
    }
#pragma unroll
    for (int i = 0; i < 12; i++) {
        int mm = ty * 12 + i;
        *(float4*)&P[(size_t)mm * 64 + tx * 4] =
            make_float4(acc[i][0], acc[i][1], acc[i][2], acc[i][3]);
    }
}

// =====================================================================
// Recurrence phase B: reduce K-slices + gates. grid 640 x 256.
//  bid<128  : caption (dir=bid>>6; jg=(bid>>2)&15; q=bid&3 -> 16 j's).
//  bid>=128 : gen (i=(bid-128)>>3; jg, q from low bits).
// =====================================================================
__global__ __launch_bounds__(256) void step_gates2(
    const float* __restrict__ pcap, const float* __restrict__ pgen,
    const float* __restrict__ giT2_f, const float* __restrict__ giT2_b,
    float* __restrict__ hfT, float* __restrict__ hbT,
    const float* __restrict__ bhh_f, const float* __restrict__ bhh_b,
    const float* __restrict__ bihAll, const float* __restrict__ bhhAll,
    const float* __restrict__ hprevT, float* __restrict__ hcurT,
    float* __restrict__ hmaxT, int step)
{
    int tid = threadIdx.x;
    int b = tid & 63;
    int bid = blockIdx.x;
    if (bid < 128) {
        int dir = bid >> 6; int rem = bid & 63;
        int jg = rem >> 2, q = rem & 3;
        const float* giT = dir ? giT2_b : giT2_f;
        float* hT        = dir ? hbT   : hfT;
        const float* bhh = dir ? bhh_b : bhh_f;
        int t  = dir ? (Tsz - 1 - step) : step;
        int tp = dir ? (t + 1) : (t - 1);
#pragma unroll
        for (int u = 0; u < 4; u++) {
            int jl = q * 16 + u * 4 + (tid >> 6);
            int j = jg * 64 + jl;
            float gh[3] = {0.f, 0.f, 0.f};
            if (step > 0) {
#pragma unroll
                for (int ks = 0; ks < 8; ks++) {
                    const float* pb = pcap + ((((size_t)dir * 8 + ks) * 16 + jg) * 192) * 64;
#pragma unroll
                    for (int g = 0; g < 3; g++)
                        gh[g] += pb[(size_t)(g * 64 + jl) * 64 + b];
                }
            }
            size_t gc = (size_t)t * 64 + b;
            float gr = giT[(size_t)j * NC + gc];
            float gz = giT[(size_t)(Lsz + j) * NC + gc];
            float gn = giT[(size_t)(2 * Lsz + j) * NC + gc];
            float hp = (step > 0) ? hT[((size_t)tp * Lsz + j) * Bsz + b] : 0.f;
            float r = sigf(gr + gh[0] + bhh[j]);
            float z = sigf(gz + gh[1] + bhh[Lsz + j]);
            float n = tanhf(gn + r * (gh[2] + bhh[2 * Lsz + j]));
            hT[((size_t)t * Lsz + j) * Bsz + b] = (1.f - z) * n + z * hp;
        }
    } else {
        int g2 = bid - 128;
        int i = g2 >> 3; int rest = g2 & 7;
        int jg = rest >> 2, q = rest & 3;
        const float* bih = bihAll + (size_t)i * R3sz;
        const float* bhh = bhhAll + (size_t)i * R3sz;
        const float* p0 = pgen + ((((size_t)i * 2 + 0) * 2 + jg) * 192) * 64;
        const float* p1 = pgen + ((((size_t)i * 2 + 1) * 2 + jg) * 192) * 64;
#pragma unroll
        for (int u = 0; u < 4; u++) {
            int jl = q * 16 + u * 4 + (tid >> 6);
            int j = jg * 64 + jl;
            float sih[3], shh[3];
#pragma unroll
            for (int g = 0; g < 3; g++) {
                sih[g] = p0[(size_t)(g * 64 + jl) * 64 + b];
                shh[g] = (step > 0) ? p1[(size_t)(g * 64 + jl) * 64 + b] : 0.f;
            }
            float r = sigf(sih[0] + bih[j] + shh[0] + bhh[j]);
            float z = sigf(sih[1] + bih[Rsz + j] + shh[1] + bhh[Rsz + j]);
            float n = tanhf(sih[2] + bih[2 * Rsz + j] + r * (shh[2] + bhh[2 * Rsz + j]));
            float hp = (step > 0) ? hprevT[((size_t)i * Rsz + j) * Bsz + b] : 0.f;
            float h = (1.f - z) * n + z * hp;
            size_t idx = ((size_t)i * Rsz + j) * Bsz + b;
            hcurT[idx] = h;
            hmaxT[idx] = (step == 0) ? h : fmaxf(hmaxT[idx], h);
        }
    }
}

// =====================================================================
// txt = (hf+hb)/2, [t][c][b] -> [b][t][c] transpose. grid (32, 16).
// =====================================================================
__global__ __launch_bounds__(256) void txt_combine(
    const float* __restrict__ hfT, const float* __restrict__ hbT,
    float* __restrict__ txt)
{
    __shared__ float s[64][65];
    int t = blockIdx.x;
    int c0 = blockIdx.y * 64;
    int tid = threadIdx.x;
#pragma unroll
    for (int l = 0; l < 16; l++) {
        int e = l * 256 + tid;
        int cc = e >> 6, b = e & 63;
        size_t idx = ((size_t)t * Lsz + c0 + cc) * Bsz + b;
        s[cc][b] = 0.5f * (hfT[idx] + hbT[idx]);
    }
    __syncthreads();
#pragma unroll
    for (int l = 0; l < 16; l++) {
        int e = l * 256 + tid;
        int b = e >> 6, cc = e & 63;
        txt[((size_t)b * Tsz + t) * Lsz + c0 + cc] = s[cc][b];
    }
}

// =====================================================================
// Self-attention: logits -> softmax -> apply + residual. grid (64, 8).
// =====================================================================
__global__ __launch_bounds__(256) void attn_kernel(
    const float* __restrict__ q, const float* __restrict__ kmat,
    const float* __restrict__ v, const float* __restrict__ txt,
    const float* __restrict__ gamma_p, float* __restrict__ xattn)
{
    __shared__ float qs[32][129];
    __shared__ float ks[32][129];
    __shared__ float As[32][33];
    int b = blockIdx.x;
    int c0 = blockIdx.y * 128;
    int tid = threadIdx.x;
    for (int e = tid; e < Tsz * Rsz; e += 256) {
        qs[e >> 7][e & 127] = q[(size_t)b * Tsz * Rsz + e];
        ks[e >> 7][e & 127] = kmat[(size_t)b * Tsz * Rsz + e];
    }
    __syncthreads();
    for (int e = tid; e < Tsz * Tsz; e += 256) {
        int t = e >> 5, ss = e & 31;
        float acc = 0.f;
#pragma unroll 4
        for (int o = 0; o < Rsz; o++) acc = fmaf(qs[t][o], ks[ss][o], acc);
        As[t][ss] = acc;
    }
    __syncthreads();
    if (tid < 32) {
        int t = tid;
        float mx = -1e30f;
#pragma unroll
        for (int ss = 0; ss < 32; ss++) mx = fmaxf(mx, As[t][ss]);
        float sum = 0.f;
        float ex[32];
#pragma unroll
        for (int ss = 0; ss < 32; ss++) { ex[ss] = __expf(As[t][ss] - mx); sum += ex[ss]; }
        float inv = 1.f / sum;
#pragma unroll
        for (int ss = 0; ss < 32; ss++) As[t][ss] = ex[ss] * inv;
    }
    __syncthreads();
    float gamma = *gamma_p;
    for (int e = tid; e < Tsz * 128; e += 256) {
        int tt = e >> 7, c = c0 + (e & 127);
        float acc = 0.f;
#pragma unroll 8
        for (int ss = 0; ss < Tsz; ss++)
            acc = fmaf(As[tt][ss], v[((size_t)b * Tsz + ss) * Lsz + c], acc);
        size_t oidx = ((size_t)b * Tsz + tt) * Lsz + c;
        xattn[oidx] = gamma * acc + txt[oidx];
    }
}

// ---------------- length-masked mean pool, grid (64,4) ----------------
__global__ __launch_bounds__(256) void pool_kernel(
    const float* __restrict__ xattn, const int* __restrict__ lens,
    float* __restrict__ txt_embed)
{
    int b = blockIdx.x;
    int c = blockIdx.y * 256 + threadIdx.x;
    int len = lens[b];
    float s = 0.f;
    for (int t = 0; t < len; t++) s += xattn[((size_t)b * Tsz + t) * Lsz + c];
    txt_embed[(size_t)b * Lsz + c] = s / (float)len;
}

// =====================================================================
// base_fc[b][n] = dot(txt_emb[b][:], W_txt_fc[n][0:1024]). grid 256.
// =====================================================================
__global__ __launch_bounds__(256) void basefc_kernel(
    const float* __restrict__ temb, const float* __restrict__ W,
    float* __restrict__ out)
{
    int lane = threadIdx.x & 63, w = threadIdx.x >> 6;
    int n = blockIdx.x * 4 + w;
    const float* wr = W + (size_t)n * (Rsz + Lsz) + lane * 16;
    float wv[16];
#pragma unroll
    for (int u = 0; u < 4; u++) *(float4*)&wv[u * 4] = *(const float4*)&wr[u * 4];
    for (int b = 0; b < Bsz; b++) {
        const float* te = temb + (size_t)b * Lsz + lane * 16;
        float tv[16];
#pragma unroll
        for (int u = 0; u < 4; u++) *(float4*)&tv[u * 4] = *(const float4*)&te[u * 4];
        float a = 0.f;
#pragma unroll
        for (int u = 0; u < 16; u++) a = fmaf(wv[u], tv[u], a);
#pragma unroll
        for (int off = 32; off; off >>= 1) a += __shfl_down(a, off, 64);
        if (lane == 0) out[(size_t)b * Lsz + n] = a;
    }
}

// ---------------- hmax [i][j][b] -> [(i*64+b)][j], grid 64 ----------------
__global__ __launch_bounds__(256) void hmax_transpose(
    const float* __restrict__ hmaxT, float* __restrict__ hstd)
{
    __shared__ float s[128][65];
    int i = blockIdx.x, tid = threadIdx.x;
#pragma unroll
    for (int l = 0; l < 32; l++) {
        int e = l * 256 + tid;
        int j = e >> 6, b = e & 63;
        s[j][b] = hmaxT[((size_t)i * Rsz + j) * Bsz + b];
    }
    __syncthreads();
#pragma unroll
    for (int l = 0; l < 32; l++) {
        int e = l * 256 + tid;
        int b = e >> 7, j = e & 127;
        hstd[((size_t)i * Bsz + b) * Rsz + j] = s[j][b];
    }
}

// ---------------- final fused l2norm + cosine, grid 4096 ----------------
__global__ __launch_bounds__(256) void sims_kernel(
    const float* __restrict__ fc_delta, const float* __restrict__ base_fc,
    const float* __restrict__ bfc, const float* __restrict__ iv,
    float* __restrict__ out)
{
    int m = blockIdx.x;          // i*64 + b
    int i = m >> 6, b = m & 63;
    int tid = threadIdx.x;
    float s1 = 0.f, s2 = 0.f;
    for (int c = tid; c < Lsz; c += 256) {
        float f = fc_delta[(size_t)m * Lsz + c] + base_fc[(size_t)b * Lsz + c] + bfc[c];
        s1 = fmaf(f, f, s1);
        s2 = fmaf(f, iv[(size_t)i * Lsz + c], s2);
    }
#pragma unroll
    for (int off = 32; off; off >>= 1) {
        s1 += __shfl_down(s1, off, 64);
        s2 += __shfl_down(s2, off, 64);
    }
    __shared__ float p1[4], p2[4];
    int w = tid >> 6;
    if ((tid & 63) == 0) { p1[w] = s1; p2[w] = s2; }
    __syncthreads();
    if (tid == 0) {
        float t1 = p1[0] + p1[1] + p1[2] + p1[3];
        float t2 = p2[0] + p2[1] + p2[2] + p2[3];
        out[m] = t2 / (sqrtf(t1) + 1e-8f);
    }
}

// =====================================================================
extern "C" void kernel_launch(void* const* d_in, const int* in_sizes, int n_in,
                              void* d_out, int out_size, void* d_ws, size_t ws_size,
                              hipStream_t stream)
{
    const float* img_embed    = (const float*)d_in[0];
    const float* cap_embed    = (const float*)d_in[1];
    const int*   lens         = (const int*)d_in[2];
    const float* W_reduce_img = (const float*)d_in[3];
    const float* b_reduce_img = (const float*)d_in[4];
    const float* W_reduce_txt = (const float*)d_in[5];
    const float* b_reduce_txt = (const float*)d_in[6];
    const float* gru_Wih_f    = (const float*)d_in[7];
    const float* gru_Whh_f    = (const float*)d_in[8];
    const float* gru_bih_f    = (const float*)d_in[9];
    const float* gru_bhh_f    = (const float*)d_in[10];
    const float* gru_Wih_b    = (const float*)d_in[11];
    const float* gru_Whh_b    = (const float*)d_in[12];
    const float* gru_bih_b    = (const float*)d_in[13];
    const float* gru_bhh_b    = (const float*)d_in[14];
    const float* sa_Wq        = (const float*)d_in[15];
    const float* sa_bq        = (const float*)d_in[16];
    const float* sa_Wk        = (const float*)d_in[17];
    const float* sa_bk        = (const float*)d_in[18];
    const float* sa_Wv        = (const float*)d_in[19];
    const float* sa_bv        = (const float*)d_in[20];
    const float* sa_gamma     = (const float*)d_in[21];
    const float* gen_Wih      = (const float*)d_in[22];
    const float* gen_bih      = (const float*)d_in[23];
    const float* gen_Whh      = (const float*)d_in[24];
    const float* gen_bhh      = (const float*)d_in[25];
    const float* gen_Wbih     = (const float*)d_in[26];
    const float* gen_bbih     = (const float*)d_in[27];
    const float* gen_Wbhh     = (const float*)d_in[28];
    const float* gen_bbhh     = (const float*)d_in[29];
    const float* W_txt_fc     = (const float*)d_in[30];
    const float* b_txt_fc     = (const float*)d_in[31];

    float* ws = (float*)d_ws;
    size_t off = 0;
    auto alloc = [&](size_t n) { float* p = ws + off; off += n; return p; };
    float* giT2_b   = alloc((size_t)H3sz * NC);          // [3072][2048]
    float* hfT      = alloc((size_t)Tsz * Lsz * Bsz);
    float* hbT      = alloc((size_t)Tsz * Lsz * Bsz);
    float* capTr    = alloc((size_t)KPAD * NC);
    float* capT2    = alloc((size_t)Rsz * NC);
    float* txt      = alloc((size_t)Bsz * Tsz * Lsz);
    float* qbuf     = alloc((size_t)Bsz * Tsz * Rsz);
    float* kbuf     = alloc((size_t)Bsz * Tsz * Rsz);
    float* vbuf     = alloc((size_t)Bsz * Tsz * Lsz);
    float* xattn    = alloc((size_t)Bsz * Tsz * Lsz);
    float* txt_emb  = alloc((size_t)Bsz * Lsz);
    float* base     = alloc((size_t)Bsz * Rsz);
    float* iv       = alloc((size_t)Bsz * Lsz);
    float* WihAll   = alloc((size_t)Bsz * GENROWS);      // raw gen weights
    float* WhhAll   = alloc((size_t)Bsz * GENROWS);
    float* WihAllT  = alloc((size_t)Bsz * GENROWS);      // [i][128][384]
    float* WhhAllT  = alloc((size_t)Bsz * GENROWS);
    float* WhhT_f   = alloc((size_t)Lsz * H3sz);         // [1024][3072]
    float* WhhT_b   = alloc((size_t)Lsz * H3sz);
    float* WihT_f   = alloc((size_t)KPAD * H3sz);        // [304][3072]
    float* WihT_b   = alloc((size_t)KPAD * H3sz);
    float* WrtT     = alloc((size_t)KPAD * Rsz);         // [304][128]
    float* bihAll   = alloc((size_t)Bsz * R3sz);
    float* bhhAll   = alloc((size_t)Bsz * R3sz);
    float* hA       = alloc((size_t)Bsz * Rsz * Bsz);
    float* hB       = alloc((size_t)Bsz * Rsz * Bsz);
    float* hmaxT    = alloc((size_t)Bsz * Rsz * Bsz);
    float* hstd     = alloc((size_t)Bsz * Bsz * Rsz);
    float* base_fc  = alloc((size_t)Bsz * Lsz);
    float* fc_delta = alloc((size_t)Bsz * Bsz * Lsz);
    // Aliases (disjoint lifetimes):
    //  giT2_f (6.29M floats) reuses WihAll+WhhAll (exactly 6.29M, contiguous)
    //  — written by the gi GEMM strictly AFTER trans_gen consumed the raw
    //  gen weights. pcap/pgen alias fc_delta/vbuf as before.
    float* giT2_f = WihAll;
    float* pcap = fc_delta;   // 3.15M floats in fc_delta (4.19M)
    float* pgen = vbuf;       // 3.15M floats in vbuf+xattn (4.19M)

    // 1) one-time weight transposes (all independent)
    transp_kernel<<<dim3(16, 48), 256, 0, stream>>>(gru_Whh_f, WhhT_f, H3sz, Lsz, Lsz);
    transp_kernel<<<dim3(16, 48), 256, 0, stream>>>(gru_Whh_b, WhhT_b, H3sz, Lsz, Lsz);
    transp_kernel<<<dim3(5, 48), 256, 0, stream>>>(gru_Wih_f, WihT_f, H3sz, DIN, KPAD);
    transp_kernel<<<dim3(5, 48), 256, 0, stream>>>(gru_Wih_b, WihT_b, H3sz, DIN, KPAD);
    transp_kernel<<<dim3(5, 2), 256, 0, stream>>>(W_reduce_txt, WrtT, Rsz, DIN, KPAD);
    captr_kernel<<<dim3(32, 5), 256, 0, stream>>>(cap_embed, capTr);

    // 2) image-side precompute + generated weights (+ their transposes)
    img_kernel<<<64, 256, 0, stream>>>(img_embed, W_reduce_img, b_reduce_img, base, iv);
    genw_kernel<<<dim3(194, 2), 256, 0, stream>>>(gen_Wih, gen_bih, gen_Whh, gen_bhh,
        gen_Wbih, gen_bbih, gen_Wbhh, gen_bbhh, base, WihAll, WhhAll, bihAll, bhhAll);
    trans_gen<<<dim3(2, 6, 128), 256, 0, stream>>>(WihAll, WhhAll, WihAllT, WhhAllT);

    // 3) gi (both dirs) + cap_reduced — all-transposed GEMM, fully coalesced.
    //    NOTE: giT2_f aliases WihAll/WhhAll, so this must come after trans_gen.
    gemm_tt<<<dim3(16, 24, 2), 256, 0, stream>>>(WihT_f, WihT_b, capTr,
        gru_bih_f, gru_bih_b, giT2_f, giT2_b, H3sz);
    gemm_tt<<<dim3(16, 1, 1), 256, 0, stream>>>(WrtT, WrtT, capTr,
        b_reduce_txt, b_reduce_txt, capT2, capT2, Rsz);

    // 4) recurrences: vectorized per-step GEMM (512x256) + gates (640x256)
    for (int s = 0; s < Tsz; s++) {
        const float* hp = (s & 1) ? hA : hB;   // unused at s==0
        float* hc = (s & 1) ? hB : hA;
        if (s == 0) hp = hA;
        step_gemm2<<<512, 256, 0, stream>>>(hfT, hbT, WhhT_f, WhhT_b,
            capT2, WihAllT, WhhAllT, hp, pcap, pgen, s);
        step_gates2<<<640, 256, 0, stream>>>(pcap, pgen, giT2_f, giT2_b, hfT, hbT,
            gru_bhh_f, gru_bhh_b, bihAll, bhhAll, hp, hc, hmaxT, s);
    }
    hmax_transpose<<<64, 256, 0, stream>>>(hmaxT, hstd);

    // 5) combine + self-attention
    txt_combine<<<dim3(32, 16), 256, 0, stream>>>(hfT, hbT, txt);
    gemm_bias<<<dim3(2, 32, 2), 256, 0, stream>>>(txt, Lsz, sa_Wq, sa_Wk, Lsz, 0,
        sa_bq, sa_bk, qbuf, kbuf, Bsz * Tsz, Rsz, Lsz);
    gemm_bias<<<dim3(16, 32), 256, 0, stream>>>(txt, Lsz, sa_Wv, sa_Wv, Lsz, 0,
        sa_bv, sa_bv, vbuf, vbuf, Bsz * Tsz, Lsz, Lsz);
    attn_kernel<<<dim3(64, 8), 256, 0, stream>>>(qbuf, kbuf, vbuf, txt, sa_gamma, xattn);

    // 6) pool + image-independent FC part
    pool_kernel<<<dim3(64, 4), 256, 0, stream>>>(xattn, lens, txt_emb);
    basefc_kernel<<<256, 256, 0, stream>>>(txt_emb, W_txt_fc, base_fc);

    // 7) per-(image,caption) FC delta + fused norm/cosine
    gemm_bias<<<dim3(16, 64), 256, 0, stream>>>(hstd, Rsz, W_txt_fc, W_txt_fc,
        Rsz + Lsz, Lsz, nullptr, nullptr, fc_delta, fc_delta, Bsz * Bsz, Lsz, Rsz);
    sims_kernel<<<4096, 256, 0, stream>>>(fc_delta, base_fc, b_txt_fc, iv, (float*)d_out);
}